// Round 4
// baseline (146.712 us; speedup 1.0000x reference)
//
#include <hip/hip_runtime.h>
#include <stdint.h>

#define EPSF 1e-6f

typedef unsigned short u16;
typedef __attribute__((ext_vector_type(8))) u16 u16x8;
typedef __attribute__((ext_vector_type(8))) __bf16 bf16x8;
typedef __attribute__((ext_vector_type(4))) float f32x4;

static constexpr int NBI = 128, NBT = 128, KI = 36, LC = 50, DD = 1024;
static constexpr int NEL = KI * LC;   // 1800
static constexpr int GM  = NBI * KI;  // 4608
static constexpr int GN  = NBT * LC;  // 6400
static constexpr int BM = 256, BN = 256, BK = 64;
static constexpr int KT  = DD / BK;   // 16
static constexpr int MT  = GM / BM;   // 18
static constexpr int NTT = GN / BN;   // 25
static constexpr int TB  = BM * BK;   // 16384 elems

static __device__ __forceinline__ u16 f2bf(float f) {  // RNE
  uint32_t u = __float_as_uint(f);
  u += 0x7fffu + ((u >> 16) & 1u);
  return (u16)(u >> 16);
}
static __device__ __forceinline__ float bf2f(u16 h) {
  return __uint_as_float((uint32_t)h << 16);
}

typedef __attribute__((address_space(1))) void gv_t;
typedef __attribute__((address_space(3))) void lv_t;
static __device__ __forceinline__ void gload16(const void* g, void* l) {
  __builtin_amdgcn_global_load_lds((const gv_t*)g, (lv_t*)l, 16, 0, 0);
}

// ---------------- kernel 0: add EPS, L2-normalize rows, cast to bf16 ----------------
__global__ __launch_bounds__(256) void hcam_normcast(
    const float* __restrict__ imgs, const float* __restrict__ caps,
    u16* __restrict__ A, u16* __restrict__ B) {
  int r = blockIdx.x;
  const float* src; u16* dst;
  if (r < GM) { src = imgs + (size_t)r * DD;        dst = A + (size_t)r * DD; }
  else        { src = caps + (size_t)(r - GM) * DD; dst = B + (size_t)(r - GM) * DD; }
  int tid = threadIdx.x;
  float4 v = *(const float4*)(src + tid * 4);
  v.x += EPSF; v.y += EPSF; v.z += EPSF; v.w += EPSF;
  float ss = v.x * v.x + v.y * v.y + v.z * v.z + v.w * v.w;
  #pragma unroll
  for (int m = 32; m; m >>= 1) ss += __shfl_xor(ss, m);
  __shared__ float wsum[4];
  if ((tid & 63) == 0) wsum[tid >> 6] = ss;
  __syncthreads();
  float inv = 1.0f / sqrtf(wsum[0] + wsum[1] + wsum[2] + wsum[3]);
  ushort4 o = make_ushort4(f2bf(v.x * inv), f2bf(v.y * inv), f2bf(v.z * inv), f2bf(v.w * inv));
  *(ushort4*)(dst + tid * 4) = o;
}

// ---------------- kernel 1: C = A * B^T, 256x256, BK=64, true 8-phase schedule ------
// Per K-tile t: 4 phases, each {12 ds_read; stage 1 half-tile; s_barrier; lgkmcnt(0);
// setprio(1); 16 MFMA; setprio(0); s_barrier}. Stage rotation: ph0:B-h0(t+1),
// ph1:A-h1(t+1), ph2:B-h1(t+1), ph3:A-h0(t+2). Counted vmcnt(2) at END of ph3
// (before trailing barrier): oldest 8 outstanding loads = all of tile t+1; the
// just-issued A-h0(t+2) pair stays in flight. Trailing ph3 barrier = tile-ready
// for t+1, so every phase's ds_reads are race-free. Swizzle as before (rule #21).
__global__ __launch_bounds__(512, 2) void hcam_gemm8(
    const u16* __restrict__ A, const u16* __restrict__ B, float* __restrict__ C) {
  __shared__ u16 As[2 * TB];
  __shared__ u16 Bs[2 * TB];

  const int nwg = MT * NTT;
  int orig = blockIdx.x;
  int qq = nwg >> 3, rr = nwg & 7;
  int xcd = orig & 7, idx = orig >> 3;
  int wg = (xcd < rr ? xcd * (qq + 1) : rr * (qq + 1) + (xcd - rr) * qq) + idx;
  const int bm = wg % MT, bn = wg / MT;

  const int tid = threadIdx.x, lane = tid & 63, w = tid >> 6;
  const int wm = w >> 2, wn = w & 3;
  const u16* Ag = A + (size_t)(bm * BM) * DD;
  const u16* Bg = B + (size_t)(bn * BN) * DD;

  const int srow = tid >> 3;
  const int sc16 = (tid & 7) ^ (srow & 7);
  const int wbase = w * 8;

  // stage one half-tile (128 rows x BK) = 2 gload16/thread
  auto stage = [&](const u16* g, u16* lds, int kt, int h) {
    #pragma unroll
    for (int j = 0; j < 2; ++j) {
      int row = h * 128 + j * 64 + srow;
      gload16(g + (size_t)row * DD + kt * BK + sc16 * 8,
              lds + (h * 128 + j * 64 + wbase) * BK);
    }
  };

  f32x4 acc[8][4];
  #pragma unroll
  for (int i = 0; i < 8; ++i)
    #pragma unroll
    for (int j = 0; j < 4; ++j) acc[i][j] = (f32x4){0.f, 0.f, 0.f, 0.f};

  const int fr = lane & 15, g4 = lane >> 4;

  // prologue: tile 0 (4 halves) + A-h0 of tile 1 -> 10 loads in flight
  stage(Ag, As, 0, 0); stage(Bg, Bs, 0, 0);
  stage(Ag, As, 0, 1); stage(Bg, Bs, 0, 1);
  stage(Ag, As + TB, 1, 0);
  asm volatile("s_waitcnt vmcnt(2)" ::: "memory");   // tile 0 landed
  __builtin_amdgcn_s_barrier();                      // tile-ready(0)
  __builtin_amdgcn_sched_barrier(0);

  auto tile = [&](int t, u16* as_c, u16* bs_c, u16* as_n, u16* bs_n,
                  u16* as_n2) {
    const int tn = t + 1;
    #pragma unroll
    for (int ph = 0; ph < 4; ++ph) {
      const int mh = (ph == 0 || ph == 3) ? 0 : 1;   // Q00,Q10,Q11,Q01
      const int nh = (ph >= 2) ? 1 : 0;
      bf16x8 af[2][4], bfv[2][2];
      #pragma unroll
      for (int k2 = 0; k2 < 2; ++k2) {
        const int c16 = k2 * 4 + g4;
        const int cs = (c16 ^ (fr & 7)) << 3;
        #pragma unroll
        for (int mi = 0; mi < 4; ++mi) {
          int rowl = wm * 128 + mh * 64 + mi * 16 + fr;
          af[k2][mi] = __builtin_bit_cast(bf16x8, *(const u16x8*)(as_c + rowl * BK + cs));
        }
        #pragma unroll
        for (int ni = 0; ni < 2; ++ni) {
          int rowl = wn * 64 + nh * 32 + ni * 16 + fr;
          bfv[k2][ni] = __builtin_bit_cast(bf16x8, *(const u16x8*)(bs_c + rowl * BK + cs));
        }
      }
      // stage rotation for deep pipeline
      if (ph == 0 && tn < KT)      stage(Bg, bs_n, tn, 0);
      else if (ph == 1 && tn < KT) stage(Ag, as_n, tn, 1);
      else if (ph == 2 && tn < KT) stage(Bg, bs_n, tn, 1);
      else if (ph == 3 && t + 2 < KT) stage(Ag, as_n2, t + 2, 0);

      __builtin_amdgcn_s_barrier();                  // leading: align waves pre-MFMA
      asm volatile("s_waitcnt lgkmcnt(0)" ::: "memory");
      __builtin_amdgcn_sched_barrier(0);
      __builtin_amdgcn_s_setprio(1);
      #pragma unroll
      for (int k2 = 0; k2 < 2; ++k2)
        #pragma unroll
        for (int mi = 0; mi < 4; ++mi)
          #pragma unroll
          for (int ni = 0; ni < 2; ++ni)
            acc[mh * 4 + mi][nh * 2 + ni] = __builtin_amdgcn_mfma_f32_16x16x32_bf16(
                af[k2][mi], bfv[k2][ni], acc[mh * 4 + mi][nh * 2 + ni], 0, 0, 0);
      __builtin_amdgcn_s_setprio(0);
      if (ph == 3) {
        if (t + 2 < KT) { asm volatile("s_waitcnt vmcnt(2)" ::: "memory"); }
        else            { asm volatile("s_waitcnt vmcnt(0)" ::: "memory"); }
      }
      __builtin_amdgcn_s_barrier();                  // trailing (ph3: tile-ready t+1)
      __builtin_amdgcn_sched_barrier(0);
    }
  };

  #pragma unroll 1
  for (int tp = 0; tp < KT; tp += 2) {
    tile(tp,     As,      Bs,      As + TB, Bs + TB, As);
    tile(tp + 1, As + TB, Bs + TB, As,      Bs,      As + TB);
  }

  const int fc = lane & 15, fq = (lane >> 4) * 4;
  #pragma unroll
  for (int am = 0; am < 8; ++am) {
    #pragma unroll
    for (int an = 0; an < 4; ++an) {
      const int row0 = bm * BM + wm * 128 + am * 16 + fq;
      const int col  = bn * BN + wn * 64 + an * 16 + fc;
      #pragma unroll
      for (int j = 0; j < 4; ++j)
        C[(size_t)(row0 + j) * GN + col] = acc[am][an][j];
    }
  }
}

// ---------------- kernel 2: wave-per-row sparsemax + weighted sum ----------------
static constexpr int RPT = (NEL + 63) / 64;   // 29

__global__ __launch_bounds__(256) void hcam_spmax_w(
    const float* __restrict__ C, const int* __restrict__ ilen, const int* __restrict__ clen,
    float* __restrict__ out) {
  const int wid  = blockIdx.x * 4 + (threadIdx.x >> 6);
  const int lane = threadIdx.x & 63;
  const int i = wid >> 7, t = wid & 127;
  const int il = ilen[i], cl = clen[t];
  const float* base = C + (size_t)i * KI * GN + t * LC;

  float v[RPT];
  float sum = 0.f;
  #pragma unroll
  for (int r = 0; r < RPT; ++r) {
    int p = lane + (r << 6);
    float x = -1e30f;
    if (p < NEL) {
      int k = p / LC, l = p - k * LC;
      if (k < il && l < cl) { x = base[(size_t)k * GN + l]; sum += x; }
    }
    v[r] = x;
  }
  #pragma unroll
  for (int m = 32; m; m >>= 1) sum += __shfl_xor(sum, m);

  const float mzero = (float)(NEL - il * cl);
  float tau  = (sum - 1.0f) * (1.0f / NEL);
  float prev = (float)NEL;
  for (int it = 0; it < 32; ++it) {
    float ss = 0.f, cc = 0.f;
    #pragma unroll
    for (int r = 0; r < RPT; ++r) {
      if (v[r] > tau) { ss += v[r]; cc += 1.0f; }
    }
    #pragma unroll
    for (int m = 32; m; m >>= 1) { ss += __shfl_xor(ss, m); cc += __shfl_xor(cc, m); }
    if (tau < 0.f) cc += mzero;
    if (cc == prev || cc < 1.0f) break;
    float tn = (ss - 1.0f) / cc;
    prev = cc;
    if (tn <= tau) break;
    tau = tn;
  }

  float o = 0.f;
  #pragma unroll
  for (int r = 0; r < RPT; ++r) {
    float d = v[r] - tau;
    if (d > 0.f) o += v[r] * d;
  }
  #pragma unroll
  for (int m = 32; m; m >>= 1) o += __shfl_xor(o, m);
  if (lane == 0) out[wid] = o;
}

// ---------------- block reduction of two floats (fallback path) ----------------
static __device__ __forceinline__ void bred2(float& a, float& b2, int tid, float* red) {
  #pragma unroll
  for (int m = 32; m; m >>= 1) { a += __shfl_xor(a, m); b2 += __shfl_xor(b2, m); }
  __syncthreads();
  if ((tid & 63) == 0) { red[(tid >> 6) * 2] = a; red[(tid >> 6) * 2 + 1] = b2; }
  __syncthreads();
  a  = red[0] + red[2] + red[4] + red[6];
  b2 = red[1] + red[3] + red[5] + red[7];
}

static __device__ __forceinline__ void sparsemax_out(float vals[8], int tid, float* red, float* outp) {
  float s = 0.f, d = 0.f;
  #pragma unroll
  for (int r = 0; r < 8; ++r) { int p = tid + (r << 8); if (p < NEL) s += vals[r]; }
  bred2(s, d, tid, red);
  float tau  = (s - 1.0f) * (1.0f / NEL);
  float prev = (float)NEL;
  for (int it = 0; it < 64; ++it) {
    float ss = 0.f, cc = 0.f;
    #pragma unroll
    for (int r = 0; r < 8; ++r) {
      int p = tid + (r << 8);
      if (p < NEL && vals[r] > tau) { ss += vals[r]; cc += 1.0f; }
    }
    bred2(ss, cc, tid, red);
    if (cc == prev || cc < 1.0f) break;
    float tn = (ss - 1.0f) / cc;
    prev = cc;
    if (tn <= tau) break;
    tau = tn;
  }
  float o = 0.f; d = 0.f;
  #pragma unroll
  for (int r = 0; r < 8; ++r) {
    float v = vals[r], a2 = v - tau;
    if (a2 > 0.f) o += v * a2;
  }
  bred2(o, d, tid, red);
  if (tid == 0) *outp = o;
}

// ---------------- fallback tier 2: fused dots from normalized bf16 ----------------
__global__ __launch_bounds__(256) void hcam_fused_bf(
    const u16* __restrict__ A, const u16* __restrict__ B,
    const int* __restrict__ ilen, const int* __restrict__ clen, float* __restrict__ out) {
  const int b = blockIdx.x;
  const int i = b >> 7, t = b & 127;
  const int tid = threadIdx.x;
  const int il = ilen[i], cl = clen[t];
  float vals[8];
  #pragma unroll
  for (int r = 0; r < 8; ++r) {
    int p = tid + (r << 8);
    float v = 0.f;
    if (p < NEL) {
      int k = p / LC, l = p - k * LC;
      if (k < il && l < cl) {
        const u16* ar = A + (size_t)(i * KI + k) * DD;
        const u16* br = B + (size_t)(t * LC + l) * DD;
        float s = 0.f;
        for (int dd = 0; dd < DD; dd += 8) {
          u16x8 av = *(const u16x8*)(ar + dd);
          u16x8 bv = *(const u16x8*)(br + dd);
          #pragma unroll
          for (int q = 0; q < 8; ++q) s += bf2f(av[q]) * bf2f(bv[q]);
        }
        v = s;
      }
    }
    vals[r] = v;
  }
  __shared__ float red[8];
  sparsemax_out(vals, tid, red, &out[b]);
}

// ---------------- fallback tier 3: fully fused, norms recomputed ----------------
__global__ __launch_bounds__(256) void hcam_fused_raw(
    const float* __restrict__ imgs, const float* __restrict__ caps,
    const int* __restrict__ ilen, const int* __restrict__ clen, float* __restrict__ out) {
  const int b = blockIdx.x;
  const int i = b >> 7, t = b & 127;
  const int tid = threadIdx.x;
  const int w = tid >> 6, lane = tid & 63;
  __shared__ float inv[KI + LC];
  for (int row = w; row < KI + LC; row += 4) {
    const float* src = (row < KI) ? imgs + (size_t)(i * KI + row) * DD
                                  : caps + (size_t)(t * LC + (row - KI)) * DD;
    float ss = 0.f;
    for (int e = lane; e < DD; e += 64) { float x = src[e] + EPSF; ss += x * x; }
    #pragma unroll
    for (int m = 32; m; m >>= 1) ss += __shfl_xor(ss, m);
    if (lane == 0) inv[row] = 1.0f / sqrtf(ss);
  }
  __syncthreads();
  const int il = ilen[i], cl = clen[t];
  float vals[8];
  #pragma unroll
  for (int r = 0; r < 8; ++r) {
    int p = tid + (r << 8);
    float v = 0.f;
    if (p < NEL) {
      int k = p / LC, l = p - k * LC;
      if (k < il && l < cl) {
        const float* ar = imgs + (size_t)(i * KI + k) * DD;
        const float* br = caps + (size_t)(t * LC + l) * DD;
        float s = 0.f;
        for (int dd = 0; dd < DD; dd += 4) {
          float4 a4 = *(const float4*)(ar + dd);
          float4 b4 = *(const float4*)(br + dd);
          s += (a4.x + EPSF) * (b4.x + EPSF) + (a4.y + EPSF) * (b4.y + EPSF)
             + (a4.z + EPSF) * (b4.z + EPSF) + (a4.w + EPSF) * (b4.w + EPSF);
        }
        v = s * inv[k] * inv[KI + l];
      }
    }
    vals[r] = v;
  }
  __shared__ float red[8];
  sparsemax_out(vals, tid, red, &out[b]);
}

extern "C" void kernel_launch(void* const* d_in, const int* in_sizes, int n_in,
                              void* d_out, int out_size, void* d_ws, size_t ws_size,
                              hipStream_t stream) {
  (void)in_sizes; (void)n_in; (void)out_size;
  const float* imgs = (const float*)d_in[1];
  const float* caps = (const float*)d_in[3];
  const int*   ilen = (const int*)d_in[4];
  const int*   clen = (const int*)d_in[5];
  float* out = (float*)d_out;

  const size_t offB     = (size_t)GM * DD * sizeof(u16);
  const size_t offC     = offB + (size_t)GN * DD * sizeof(u16);
  const size_t needFull = offC + (size_t)GM * GN * sizeof(float);
  u16*   A = (u16*)d_ws;
  u16*   B = (u16*)((char*)d_ws + offB);
  float* C = (float*)((char*)d_ws + offC);

  if (ws_size >= needFull) {
    hcam_normcast<<<dim3(GM + GN), dim3(256), 0, stream>>>(imgs, caps, A, B);
    hcam_gemm8<<<dim3(MT * NTT), dim3(512), 0, stream>>>(A, B, C);
    hcam_spmax_w<<<dim3(NBI * NBT / 4), dim3(256), 0, stream>>>(C, ilen, clen, out);
  } else if (ws_size >= offC) {
    hcam_normcast<<<dim3(GM + GN), dim3(256), 0, stream>>>(imgs, caps, A, B);
    hcam_fused_bf<<<dim3(NBI * NBT), dim3(256), 0, stream>>>(A, B, ilen, clen, out);
  } else {
    hcam_fused_raw<<<dim3(NBI * NBT), dim3(256), 0, stream>>>(imgs, caps, ilen, clen, out);
  }
}

// Round 5
// 127.399 us; speedup vs baseline: 1.1516x; 1.1516x over previous
//
#include <hip/hip_runtime.h>
#include <stdint.h>

#define EPSF 1e-6f

typedef unsigned short u16;
typedef __attribute__((ext_vector_type(8))) u16 u16x8;
typedef __attribute__((ext_vector_type(8))) __bf16 bf16x8;
typedef __attribute__((ext_vector_type(4))) float f32x4;

static constexpr int NBI = 128, NBT = 128, KI = 36, LC = 50, DD = 1024;
static constexpr int NEL = KI * LC;   // 1800
static constexpr int GM  = NBI * KI;  // 4608
static constexpr int GN  = NBT * LC;  // 6400
static constexpr int BM = 256, BN = 256, BK = 64;
static constexpr int KT  = DD / BK;   // 16
static constexpr int MT  = GM / BM;   // 18
static constexpr int NTT = GN / BN;   // 25
static constexpr int TB  = BM * BK;   // 16384 elems

static __device__ __forceinline__ u16 f2bf(float f) {  // RNE
  uint32_t u = __float_as_uint(f);
  u += 0x7fffu + ((u >> 16) & 1u);
  return (u16)(u >> 16);
}
static __device__ __forceinline__ float bf2f(u16 h) {
  return __uint_as_float((uint32_t)h << 16);
}

typedef __attribute__((address_space(1))) void gv_t;
typedef __attribute__((address_space(3))) void lv_t;
static __device__ __forceinline__ void gload16(const void* g, void* l) {
  __builtin_amdgcn_global_load_lds((const gv_t*)g, (lv_t*)l, 16, 0, 0);
}

// ---------------- kernel 0: add EPS, L2-normalize rows, cast to bf16 ----------------
__global__ __launch_bounds__(256) void hcam_normcast(
    const float* __restrict__ imgs, const float* __restrict__ caps,
    u16* __restrict__ A, u16* __restrict__ B) {
  int r = blockIdx.x;
  const float* src; u16* dst;
  if (r < GM) { src = imgs + (size_t)r * DD;        dst = A + (size_t)r * DD; }
  else        { src = caps + (size_t)(r - GM) * DD; dst = B + (size_t)(r - GM) * DD; }
  int tid = threadIdx.x;
  float4 v = *(const float4*)(src + tid * 4);
  v.x += EPSF; v.y += EPSF; v.z += EPSF; v.w += EPSF;
  float ss = v.x * v.x + v.y * v.y + v.z * v.z + v.w * v.w;
  #pragma unroll
  for (int m = 32; m; m >>= 1) ss += __shfl_xor(ss, m);
  __shared__ float wsum[4];
  if ((tid & 63) == 0) wsum[tid >> 6] = ss;
  __syncthreads();
  float inv = 1.0f / sqrtf(wsum[0] + wsum[1] + wsum[2] + wsum[3]);
  ushort4 o = make_ushort4(f2bf(v.x * inv), f2bf(v.y * inv), f2bf(v.z * inv), f2bf(v.w * inv));
  *(ushort4*)(dst + tid * 4) = o;
}

// ---------------- kernel 1: C = A * B^T, 256x256, BK=64, 16 waves (4 waves/SIMD) ----
// R2's proven 2-barrier-per-tile schedule (R3's per-phase barriers REGRESSED: 1
// block/CU -> lockstep, no slack). 1024 threads = 16 waves of 64x64 output each ->
// 4 waves/SIMD to hide ds_read/vmcnt latency; acc = 16 f32x4/thread keeps VGPR <=128
// (required for 16-wave residency). One gload16/thread per half-tile -> vmcnt(1).
// C stored fp16 (quant err <=6e-5, halves write + spmax read traffic).
__global__ __launch_bounds__(1024, 1) void hcam_gemm16(
    const u16* __restrict__ A, const u16* __restrict__ B, _Float16* __restrict__ C) {
  __shared__ u16 As[2 * TB];
  __shared__ u16 Bs[2 * TB];

  const int nwg = MT * NTT;
  int orig = blockIdx.x;
  int qq = nwg >> 3, rr = nwg & 7;
  int xcd = orig & 7, idx = orig >> 3;
  int wg = (xcd < rr ? xcd * (qq + 1) : rr * (qq + 1) + (xcd - rr) * qq) + idx;
  const int bm = wg % MT, bn = wg / MT;

  const int tid = threadIdx.x, lane = tid & 63, w = tid >> 6;
  const int wm = w >> 2, wn = w & 3;          // 4x4 waves, 64x64 out each
  const u16* Ag = A + (size_t)(bm * BM) * DD;
  const u16* Bg = B + (size_t)(bn * BN) * DD;

  const int srow = tid >> 3;                  // 0..127
  const int sc16 = (tid & 7) ^ (srow & 7);    // inverse-swizzled col16 (rule #21)
  const int wbase = w * 8;                    // wave-uniform LDS row base (8 rows/wave)

  // stage one half-tile (128 rows x BK) = 1 gload16/thread
  auto stage = [&](const u16* g, u16* lds, int kt, int h) {
    gload16(g + (size_t)(h * 128 + srow) * DD + kt * BK + sc16 * 8,
            lds + (h * 128 + wbase) * BK);
  };

  f32x4 acc[4][4];
  #pragma unroll
  for (int i = 0; i < 4; ++i)
    #pragma unroll
    for (int j = 0; j < 4; ++j) acc[i][j] = (f32x4){0.f, 0.f, 0.f, 0.f};

  const int fr = lane & 15, g4 = lane >> 4;

  auto tile = [&](int t, u16* as_c, u16* bs_c, u16* as_n, u16* bs_n) {
    const int tn = t + 1;
    if (tn < KT) {
      stage(Ag, as_n, tn, 0);                            // A-h0(t+1)
      asm volatile("s_waitcnt vmcnt(1)" ::: "memory");   // tile t fully landed
    } else {
      asm volatile("s_waitcnt vmcnt(0)" ::: "memory");
    }
    __builtin_amdgcn_s_barrier();                        // tile-ready
    __builtin_amdgcn_sched_barrier(0);
    #pragma unroll
    for (int ph = 0; ph < 4; ++ph) {
      const int mh = (ph == 0 || ph == 3) ? 0 : 1;       // 32x32 quadrant walk
      const int nh = (ph >= 2) ? 1 : 0;
      bf16x8 af[2][2], bfv[2][2];
      #pragma unroll
      for (int k2 = 0; k2 < 2; ++k2) {
        const int c16 = k2 * 4 + g4;
        const int cs = (c16 ^ (fr & 7)) << 3;
        #pragma unroll
        for (int mi = 0; mi < 2; ++mi) {
          int rowl = wm * 64 + mh * 32 + mi * 16 + fr;
          af[k2][mi] = __builtin_bit_cast(bf16x8, *(const u16x8*)(as_c + rowl * BK + cs));
        }
        #pragma unroll
        for (int ni = 0; ni < 2; ++ni) {
          int rowl = wn * 64 + nh * 32 + ni * 16 + fr;
          bfv[k2][ni] = __builtin_bit_cast(bf16x8, *(const u16x8*)(bs_c + rowl * BK + cs));
        }
      }
      if (tn < KT) {                                     // B0,A1,B1 of t+1
        if (ph == 0)      stage(Bg, bs_n, tn, 0);
        else if (ph == 1) stage(Ag, as_n, tn, 1);
        else if (ph == 2) stage(Bg, bs_n, tn, 1);
      }
      __builtin_amdgcn_s_setprio(1);
      #pragma unroll
      for (int k2 = 0; k2 < 2; ++k2)
        #pragma unroll
        for (int mi = 0; mi < 2; ++mi)
          #pragma unroll
          for (int ni = 0; ni < 2; ++ni)
            acc[mh * 2 + mi][nh * 2 + ni] = __builtin_amdgcn_mfma_f32_16x16x32_bf16(
                af[k2][mi], bfv[k2][ni], acc[mh * 2 + mi][nh * 2 + ni], 0, 0, 0);
      __builtin_amdgcn_s_setprio(0);
    }
    __builtin_amdgcn_s_barrier();                        // reads of cur done
    __builtin_amdgcn_sched_barrier(0);
  };

  // prologue: tile 0 (4 halves) + A-h0(1) -> 5 loads/thread in flight
  stage(Ag, As, 0, 0); stage(Bg, Bs, 0, 0);
  stage(Ag, As, 0, 1); stage(Bg, Bs, 0, 1);
  stage(Ag, As + TB, 1, 0);
  // fallthrough into loop: tile() for t=0 re-issues A-h0(1)? No: loop handles all.
  // (tile(t) stages A-h0(t+1) itself; prologue's extra A-h0(1) would double-issue.)
  // -> use a dedicated first tile without the A-h0 stage:
  {
    asm volatile("s_waitcnt vmcnt(1)" ::: "memory");     // tile 0 landed
    __builtin_amdgcn_s_barrier();
    __builtin_amdgcn_sched_barrier(0);
    #pragma unroll
    for (int ph = 0; ph < 4; ++ph) {
      const int mh = (ph == 0 || ph == 3) ? 0 : 1;
      const int nh = (ph >= 2) ? 1 : 0;
      bf16x8 af[2][2], bfv[2][2];
      #pragma unroll
      for (int k2 = 0; k2 < 2; ++k2) {
        const int c16 = k2 * 4 + g4;
        const int cs = (c16 ^ (fr & 7)) << 3;
        #pragma unroll
        for (int mi = 0; mi < 2; ++mi) {
          int rowl = wm * 64 + mh * 32 + mi * 16 + fr;
          af[k2][mi] = __builtin_bit_cast(bf16x8, *(const u16x8*)(As + rowl * BK + cs));
        }
        #pragma unroll
        for (int ni = 0; ni < 2; ++ni) {
          int rowl = wn * 64 + nh * 32 + ni * 16 + fr;
          bfv[k2][ni] = __builtin_bit_cast(bf16x8, *(const u16x8*)(Bs + rowl * BK + cs));
        }
      }
      if (ph == 0)      stage(Bg, Bs + TB, 1, 0);
      else if (ph == 1) stage(Ag, As + TB, 1, 1);
      else if (ph == 2) stage(Bg, Bs + TB, 1, 1);
      __builtin_amdgcn_s_setprio(1);
      #pragma unroll
      for (int k2 = 0; k2 < 2; ++k2)
        #pragma unroll
        for (int mi = 0; mi < 2; ++mi)
          #pragma unroll
          for (int ni = 0; ni < 2; ++ni)
            acc[mh * 2 + mi][nh * 2 + ni] = __builtin_amdgcn_mfma_f32_16x16x32_bf16(
                af[k2][mi], bfv[k2][ni], acc[mh * 2 + mi][nh * 2 + ni], 0, 0, 0);
      __builtin_amdgcn_s_setprio(0);
    }
    __builtin_amdgcn_s_barrier();
    __builtin_amdgcn_sched_barrier(0);
  }

  #pragma unroll 1
  for (int tp = 1; tp + 1 < KT; tp += 2) {
    tile(tp,     As + TB, Bs + TB, As,      Bs);
    tile(tp + 1, As,      Bs,      As + TB, Bs + TB);
  }
  tile(KT - 1, As + TB, Bs + TB, As, Bs);   // KT=16: tiles 1..14 in loop, 15 here

  // C/D layout: col = lane&15, row = (lane>>4)*4 + j (m89-verified)
  const int fc = lane & 15, fq = (lane >> 4) * 4;
  #pragma unroll
  for (int am = 0; am < 4; ++am) {
    #pragma unroll
    for (int an = 0; an < 4; ++an) {
      const int row0 = bm * BM + wm * 64 + am * 16 + fq;
      const int col  = bn * BN + wn * 64 + an * 16 + fc;
      #pragma unroll
      for (int j = 0; j < 4; ++j)
        C[(size_t)(row0 + j) * GN + col] = (_Float16)acc[am][an][j];
    }
  }
}

// ---------------- kernel 2: wave-per-row sparsemax + weighted sum (fp16 C) ---------
static constexpr int RPT = (NEL + 63) / 64;   // 29

__global__ __launch_bounds__(256) void hcam_spmax_w(
    const _Float16* __restrict__ C, const int* __restrict__ ilen, const int* __restrict__ clen,
    float* __restrict__ out) {
  const int wid  = blockIdx.x * 4 + (threadIdx.x >> 6);
  const int lane = threadIdx.x & 63;
  const int i = wid >> 7, t = wid & 127;
  const int il = ilen[i], cl = clen[t];
  const _Float16* base = C + (size_t)i * KI * GN + t * LC;

  float v[RPT];
  float sum = 0.f;
  #pragma unroll
  for (int r = 0; r < RPT; ++r) {
    int p = lane + (r << 6);
    float x = -1e30f;
    if (p < NEL) {
      int k = p / LC, l = p - k * LC;
      if (k < il && l < cl) { x = (float)base[(size_t)k * GN + l]; sum += x; }
    }
    v[r] = x;
  }
  #pragma unroll
  for (int m = 32; m; m >>= 1) sum += __shfl_xor(sum, m);

  const float mzero = (float)(NEL - il * cl);
  float tau  = (sum - 1.0f) * (1.0f / NEL);
  float prev = (float)NEL;
  for (int it = 0; it < 32; ++it) {
    float ss = 0.f, cc = 0.f;
    #pragma unroll
    for (int r = 0; r < RPT; ++r) {
      if (v[r] > tau) { ss += v[r]; cc += 1.0f; }
    }
    #pragma unroll
    for (int m = 32; m; m >>= 1) { ss += __shfl_xor(ss, m); cc += __shfl_xor(cc, m); }
    if (tau < 0.f) cc += mzero;
    if (cc == prev || cc < 1.0f) break;
    float tn = (ss - 1.0f) / cc;
    prev = cc;
    if (tn <= tau) break;
    tau = tn;
  }

  float o = 0.f;
  #pragma unroll
  for (int r = 0; r < RPT; ++r) {
    float d = v[r] - tau;
    if (d > 0.f) o += v[r] * d;
  }
  #pragma unroll
  for (int m = 32; m; m >>= 1) o += __shfl_xor(o, m);
  if (lane == 0) out[wid] = o;
}

// ---------------- block reduction of two floats (fallback path) ----------------
static __device__ __forceinline__ void bred2(float& a, float& b2, int tid, float* red) {
  #pragma unroll
  for (int m = 32; m; m >>= 1) { a += __shfl_xor(a, m); b2 += __shfl_xor(b2, m); }
  __syncthreads();
  if ((tid & 63) == 0) { red[(tid >> 6) * 2] = a; red[(tid >> 6) * 2 + 1] = b2; }
  __syncthreads();
  a  = red[0] + red[2] + red[4] + red[6];
  b2 = red[1] + red[3] + red[5] + red[7];
}

static __device__ __forceinline__ void sparsemax_out(float vals[8], int tid, float* red, float* outp) {
  float s = 0.f, d = 0.f;
  #pragma unroll
  for (int r = 0; r < 8; ++r) { int p = tid + (r << 8); if (p < NEL) s += vals[r]; }
  bred2(s, d, tid, red);
  float tau  = (s - 1.0f) * (1.0f / NEL);
  float prev = (float)NEL;
  for (int it = 0; it < 64; ++it) {
    float ss = 0.f, cc = 0.f;
    #pragma unroll
    for (int r = 0; r < 8; ++r) {
      int p = tid + (r << 8);
      if (p < NEL && vals[r] > tau) { ss += vals[r]; cc += 1.0f; }
    }
    bred2(ss, cc, tid, red);
    if (cc == prev || cc < 1.0f) break;
    float tn = (ss - 1.0f) / cc;
    prev = cc;
    if (tn <= tau) break;
    tau = tn;
  }
  float o = 0.f; d = 0.f;
  #pragma unroll
  for (int r = 0; r < 8; ++r) {
    float v = vals[r], a2 = v - tau;
    if (a2 > 0.f) o += v * a2;
  }
  bred2(o, d, tid, red);
  if (tid == 0) *outp = o;
}

// ---------------- fallback tier 2: fused dots from normalized bf16 ----------------
__global__ __launch_bounds__(256) void hcam_fused_bf(
    const u16* __restrict__ A, const u16* __restrict__ B,
    const int* __restrict__ ilen, const int* __restrict__ clen, float* __restrict__ out) {
  const int b = blockIdx.x;
  const int i = b >> 7, t = b & 127;
  const int tid = threadIdx.x;
  const int il = ilen[i], cl = clen[t];
  float vals[8];
  #pragma unroll
  for (int r = 0; r < 8; ++r) {
    int p = tid + (r << 8);
    float v = 0.f;
    if (p < NEL) {
      int k = p / LC, l = p - k * LC;
      if (k < il && l < cl) {
        const u16* ar = A + (size_t)(i * KI + k) * DD;
        const u16* br = B + (size_t)(t * LC + l) * DD;
        float s = 0.f;
        for (int dd = 0; dd < DD; dd += 8) {
          u16x8 av = *(const u16x8*)(ar + dd);
          u16x8 bv = *(const u16x8*)(br + dd);
          #pragma unroll
          for (int q = 0; q < 8; ++q) s += bf2f(av[q]) * bf2f(bv[q]);
        }
        v = s;
      }
    }
    vals[r] = v;
  }
  __shared__ float red[8];
  sparsemax_out(vals, tid, red, &out[b]);
}

// ---------------- fallback tier 3: fully fused, norms recomputed ----------------
__global__ __launch_bounds__(256) void hcam_fused_raw(
    const float* __restrict__ imgs, const float* __restrict__ caps,
    const int* __restrict__ ilen, const int* __restrict__ clen, float* __restrict__ out) {
  const int b = blockIdx.x;
  const int i = b >> 7, t = b & 127;
  const int tid = threadIdx.x;
  const int w = tid >> 6, lane = tid & 63;
  __shared__ float inv[KI + LC];
  for (int row = w; row < KI + LC; row += 4) {
    const float* src = (row < KI) ? imgs + (size_t)(i * KI + row) * DD
                                  : caps + (size_t)(t * LC + (row - KI)) * DD;
    float ss = 0.f;
    for (int e = lane; e < DD; e += 64) { float x = src[e] + EPSF; ss += x * x; }
    #pragma unroll
    for (int m = 32; m; m >>= 1) ss += __shfl_xor(ss, m);
    if (lane == 0) inv[row] = 1.0f / sqrtf(ss);
  }
  __syncthreads();
  const int il = ilen[i], cl = clen[t];
  float vals[8];
  #pragma unroll
  for (int r = 0; r < 8; ++r) {
    int p = tid + (r << 8);
    float v = 0.f;
    if (p < NEL) {
      int k = p / LC, l = p - k * LC;
      if (k < il && l < cl) {
        const float* ar = imgs + (size_t)(i * KI + k) * DD;
        const float* br = caps + (size_t)(t * LC + l) * DD;
        float s = 0.f;
        for (int dd = 0; dd < DD; dd += 4) {
          float4 a4 = *(const float4*)(ar + dd);
          float4 b4 = *(const float4*)(br + dd);
          s += (a4.x + EPSF) * (b4.x + EPSF) + (a4.y + EPSF) * (b4.y + EPSF)
             + (a4.z + EPSF) * (b4.z + EPSF) + (a4.w + EPSF) * (b4.w + EPSF);
        }
        v = s * inv[k] * inv[KI + l];
      }
    }
    vals[r] = v;
  }
  __shared__ float red[8];
  sparsemax_out(vals, tid, red, &out[b]);
}

extern "C" void kernel_launch(void* const* d_in, const int* in_sizes, int n_in,
                              void* d_out, int out_size, void* d_ws, size_t ws_size,
                              hipStream_t stream) {
  (void)in_sizes; (void)n_in; (void)out_size;
  const float* imgs = (const float*)d_in[1];
  const float* caps = (const float*)d_in[3];
  const int*   ilen = (const int*)d_in[4];
  const int*   clen = (const int*)d_in[5];
  float* out = (float*)d_out;

  const size_t offB     = (size_t)GM * DD * sizeof(u16);
  const size_t offC     = offB + (size_t)GN * DD * sizeof(u16);
  const size_t needFull = offC + (size_t)GM * GN * sizeof(_Float16);
  u16*      A = (u16*)d_ws;
  u16*      B = (u16*)((char*)d_ws + offB);
  _Float16* C = (_Float16*)((char*)d_ws + offC);

  if (ws_size >= needFull) {
    hcam_normcast<<<dim3(GM + GN), dim3(256), 0, stream>>>(imgs, caps, A, B);
    hcam_gemm16<<<dim3(MT * NTT), dim3(1024), 0, stream>>>(A, B, C);
    hcam_spmax_w<<<dim3(NBI * NBT / 4), dim3(256), 0, stream>>>(C, ilen, clen, out);
  } else if (ws_size >= offC) {
    hcam_normcast<<<dim3(GM + GN), dim3(256), 0, stream>>>(imgs, caps, A, B);
    hcam_fused_bf<<<dim3(NBI * NBT), dim3(256), 0, stream>>>(A, B, ilen, clen, out);
  } else {
    hcam_fused_raw<<<dim3(NBI * NBT), dim3(256), 0, stream>>>(imgs, caps, ilen, clen, out);
  }
}

// Round 6
// 126.787 us; speedup vs baseline: 1.1572x; 1.0048x over previous
//
#include <hip/hip_runtime.h>
#include <stdint.h>

#define EPSF 1e-6f

typedef unsigned short u16;
typedef __attribute__((ext_vector_type(8))) u16 u16x8;
typedef __attribute__((ext_vector_type(8))) __bf16 bf16x8;
typedef __attribute__((ext_vector_type(4))) float f32x4;

static constexpr int NBI = 128, NBT = 128, KI = 36, LC = 50, DD = 1024;
static constexpr int NEL = KI * LC;   // 1800
static constexpr int GM  = NBI * KI;  // 4608
static constexpr int GN  = NBT * LC;  // 6400
static constexpr int BM = 256, BN = 256, BK = 64;
static constexpr int KT  = DD / BK;   // 16
static constexpr int MT  = GM / BM;   // 18
static constexpr int NTT = GN / BN;   // 25
static constexpr int TB  = BM * BK;   // 16384 elems

static __device__ __forceinline__ u16 f2bf(float f) {  // RNE
  uint32_t u = __float_as_uint(f);
  u += 0x7fffu + ((u >> 16) & 1u);
  return (u16)(u >> 16);
}
static __device__ __forceinline__ float bf2f(u16 h) {
  return __uint_as_float((uint32_t)h << 16);
}

typedef __attribute__((address_space(1))) void gv_t;
typedef __attribute__((address_space(3))) void lv_t;
static __device__ __forceinline__ void gload16(const void* g, void* l) {
  __builtin_amdgcn_global_load_lds((const gv_t*)g, (lv_t*)l, 16, 0, 0);
}

// ---------------- kernel 0: add EPS, L2-normalize rows, cast to bf16 ----------------
__global__ __launch_bounds__(256) void hcam_normcast(
    const float* __restrict__ imgs, const float* __restrict__ caps,
    u16* __restrict__ A, u16* __restrict__ B) {
  int r = blockIdx.x;
  const float* src; u16* dst;
  if (r < GM) { src = imgs + (size_t)r * DD;        dst = A + (size_t)r * DD; }
  else        { src = caps + (size_t)(r - GM) * DD; dst = B + (size_t)(r - GM) * DD; }
  int tid = threadIdx.x;
  float4 v = *(const float4*)(src + tid * 4);
  v.x += EPSF; v.y += EPSF; v.z += EPSF; v.w += EPSF;
  float ss = v.x * v.x + v.y * v.y + v.z * v.z + v.w * v.w;
  #pragma unroll
  for (int m = 32; m; m >>= 1) ss += __shfl_xor(ss, m);
  __shared__ float wsum[4];
  if ((tid & 63) == 0) wsum[tid >> 6] = ss;
  __syncthreads();
  float inv = 1.0f / sqrtf(wsum[0] + wsum[1] + wsum[2] + wsum[3]);
  ushort4 o = make_ushort4(f2bf(v.x * inv), f2bf(v.y * inv), f2bf(v.z * inv), f2bf(v.w * inv));
  *(ushort4*)(dst + tid * 4) = o;
}

// ---------------- kernel 1: C = A * B^T, 256x256, BK=64, 16 waves, k2-outer --------
// LDS-BW-bound analysis (R4 post-mortem): quadrant-phase re-reads cost 1.0 KB LDS
// per MFMA -> 31% duty ceiling. This version: per k2-half, load 4 A-frags + 4
// B-frags (8 ds_read_b128), fire the full 4x4 = 16 MFMA -> 0.5 KB/MFMA, ceiling
// ~60%. Frags 32 VGPR + acc 64 fits <=128 VGPR (4 waves/SIMD residency).
// Schedule: R2/R4's proven 2-barrier-per-tile + counted vmcnt(1).
__global__ __launch_bounds__(1024, 1) void hcam_gemm16(
    const u16* __restrict__ A, const u16* __restrict__ B, _Float16* __restrict__ C) {
  __shared__ u16 As[2 * TB];
  __shared__ u16 Bs[2 * TB];

  const int nwg = MT * NTT;
  int orig = blockIdx.x;
  int qq = nwg >> 3, rr = nwg & 7;
  int xcd = orig & 7, idx = orig >> 3;
  int wg = (xcd < rr ? xcd * (qq + 1) : rr * (qq + 1) + (xcd - rr) * qq) + idx;
  const int bm = wg % MT, bn = wg / MT;

  const int tid = threadIdx.x, lane = tid & 63, w = tid >> 6;
  const int wm = w >> 2, wn = w & 3;          // 4x4 waves, 64x64 out each
  const u16* Ag = A + (size_t)(bm * BM) * DD;
  const u16* Bg = B + (size_t)(bn * BN) * DD;

  const int srow = tid >> 3;                  // 0..127
  const int sc16 = (tid & 7) ^ (srow & 7);    // inverse-swizzled col16 (rule #21)
  const int wbase = w * 8;                    // wave-uniform LDS row base

  // stage one half-tile (128 rows x BK) = 1 gload16/thread
  auto stage = [&](const u16* g, u16* lds, int kt, int h) {
    gload16(g + (size_t)(h * 128 + srow) * DD + kt * BK + sc16 * 8,
            lds + (h * 128 + wbase) * BK);
  };

  f32x4 acc[4][4];
  #pragma unroll
  for (int i = 0; i < 4; ++i)
    #pragma unroll
    for (int j = 0; j < 4; ++j) acc[i][j] = (f32x4){0.f, 0.f, 0.f, 0.f};

  const int fr = lane & 15, g4 = lane >> 4;

  // one K-tile of compute: k2-outer, 8 ds_read + 16 MFMA per k2 (0.5 KB/MFMA)
  auto ktile_compute = [&](const u16* as_c, const u16* bs_c, bool st,
                           u16* as_n, u16* bs_n, int tn) {
    #pragma unroll
    for (int k2 = 0; k2 < 2; ++k2) {
      const int c16 = k2 * 4 + g4;
      const int cs = (c16 ^ (fr & 7)) << 3;
      bf16x8 af[4], bfv[4];
      #pragma unroll
      for (int mi = 0; mi < 4; ++mi) {
        int rowl = wm * 64 + mi * 16 + fr;
        af[mi] = __builtin_bit_cast(bf16x8, *(const u16x8*)(as_c + rowl * BK + cs));
      }
      #pragma unroll
      for (int ni = 0; ni < 4; ++ni) {
        int rowl = wn * 64 + ni * 16 + fr;
        bfv[ni] = __builtin_bit_cast(bf16x8, *(const u16x8*)(bs_c + rowl * BK + cs));
      }
      if (st) {                               // spread next-tile staging
        if (k2 == 0) { stage(Bg, bs_n, tn, 0); }
        else         { stage(Ag, as_n, tn, 1); stage(Bg, bs_n, tn, 1); }
      }
      __builtin_amdgcn_s_setprio(1);
      #pragma unroll
      for (int mi = 0; mi < 4; ++mi)
        #pragma unroll
        for (int ni = 0; ni < 4; ++ni)
          acc[mi][ni] = __builtin_amdgcn_mfma_f32_16x16x32_bf16(
              af[mi], bfv[ni], acc[mi][ni], 0, 0, 0);
      __builtin_amdgcn_s_setprio(0);
    }
  };

  auto tile = [&](int t, const u16* as_c, const u16* bs_c, u16* as_n, u16* bs_n) {
    const int tn = t + 1;
    if (tn < KT) {
      stage(Ag, as_n, tn, 0);                            // A-h0(t+1)
      asm volatile("s_waitcnt vmcnt(1)" ::: "memory");   // tile t fully landed
    } else {
      asm volatile("s_waitcnt vmcnt(0)" ::: "memory");
    }
    __builtin_amdgcn_s_barrier();                        // tile-ready
    __builtin_amdgcn_sched_barrier(0);
    ktile_compute(as_c, bs_c, tn < KT, as_n, bs_n, tn);
    __builtin_amdgcn_s_barrier();                        // reads of cur done
    __builtin_amdgcn_sched_barrier(0);
  };

  // prologue: tile 0 (4 halves) + A-h0(1) -> 5 loads/thread in flight
  stage(Ag, As, 0, 0); stage(Bg, Bs, 0, 0);
  stage(Ag, As, 0, 1); stage(Bg, Bs, 0, 1);
  stage(Ag, As + TB, 1, 0);
  // tile 0 (A-h0(1) already issued above)
  asm volatile("s_waitcnt vmcnt(1)" ::: "memory");
  __builtin_amdgcn_s_barrier();
  __builtin_amdgcn_sched_barrier(0);
  ktile_compute(As, Bs, true, As + TB, Bs + TB, 1);
  __builtin_amdgcn_s_barrier();
  __builtin_amdgcn_sched_barrier(0);

  #pragma unroll 1
  for (int tp = 1; tp + 1 < KT; tp += 2) {
    tile(tp,     As + TB, Bs + TB, As,      Bs);
    tile(tp + 1, As,      Bs,      As + TB, Bs + TB);
  }
  tile(KT - 1, As + TB, Bs + TB, As, Bs);   // tile 15

  // C/D layout: col = lane&15, row = (lane>>4)*4 + j (m89-verified)
  const int fc = lane & 15, fq = (lane >> 4) * 4;
  #pragma unroll
  for (int am = 0; am < 4; ++am) {
    #pragma unroll
    for (int an = 0; an < 4; ++an) {
      const int row0 = bm * BM + wm * 64 + am * 16 + fq;
      const int col  = bn * BN + wn * 64 + an * 16 + fc;
      #pragma unroll
      for (int j = 0; j < 4; ++j)
        C[(size_t)(row0 + j) * GN + col] = (_Float16)acc[am][an][j];
    }
  }
}

// ---------------- kernel 2: wave-per-row sparsemax + weighted sum (fp16 C) ---------
static constexpr int RPT = (NEL + 63) / 64;   // 29

__global__ __launch_bounds__(256) void hcam_spmax_w(
    const _Float16* __restrict__ C, const int* __restrict__ ilen, const int* __restrict__ clen,
    float* __restrict__ out) {
  const int wid  = blockIdx.x * 4 + (threadIdx.x >> 6);
  const int lane = threadIdx.x & 63;
  const int i = wid >> 7, t = wid & 127;
  const int il = ilen[i], cl = clen[t];
  const _Float16* base = C + (size_t)i * KI * GN + t * LC;

  float v[RPT];
  float sum = 0.f;
  #pragma unroll
  for (int r = 0; r < RPT; ++r) {
    int p = lane + (r << 6);
    float x = -1e30f;
    if (p < NEL) {
      int k = p / LC, l = p - k * LC;
      if (k < il && l < cl) { x = (float)base[(size_t)k * GN + l]; sum += x; }
    }
    v[r] = x;
  }
  #pragma unroll
  for (int m = 32; m; m >>= 1) sum += __shfl_xor(sum, m);

  const float mzero = (float)(NEL - il * cl);
  float tau  = (sum - 1.0f) * (1.0f / NEL);
  float prev = (float)NEL;
  for (int it = 0; it < 32; ++it) {
    float ss = 0.f, cc = 0.f;
    #pragma unroll
    for (int r = 0; r < RPT; ++r) {
      if (v[r] > tau) { ss += v[r]; cc += 1.0f; }
    }
    #pragma unroll
    for (int m = 32; m; m >>= 1) { ss += __shfl_xor(ss, m); cc += __shfl_xor(cc, m); }
    if (tau < 0.f) cc += mzero;
    if (cc == prev || cc < 1.0f) break;
    float tn = (ss - 1.0f) / cc;
    prev = cc;
    if (tn <= tau) break;
    tau = tn;
  }

  float o = 0.f;
  #pragma unroll
  for (int r = 0; r < RPT; ++r) {
    float d = v[r] - tau;
    if (d > 0.f) o += v[r] * d;
  }
  #pragma unroll
  for (int m = 32; m; m >>= 1) o += __shfl_xor(o, m);
  if (lane == 0) out[wid] = o;
}

// ---------------- block reduction of two floats (fallback path) ----------------
static __device__ __forceinline__ void bred2(float& a, float& b2, int tid, float* red) {
  #pragma unroll
  for (int m = 32; m; m >>= 1) { a += __shfl_xor(a, m); b2 += __shfl_xor(b2, m); }
  __syncthreads();
  if ((tid & 63) == 0) { red[(tid >> 6) * 2] = a; red[(tid >> 6) * 2 + 1] = b2; }
  __syncthreads();
  a  = red[0] + red[2] + red[4] + red[6];
  b2 = red[1] + red[3] + red[5] + red[7];
}

static __device__ __forceinline__ void sparsemax_out(float vals[8], int tid, float* red, float* outp) {
  float s = 0.f, d = 0.f;
  #pragma unroll
  for (int r = 0; r < 8; ++r) { int p = tid + (r << 8); if (p < NEL) s += vals[r]; }
  bred2(s, d, tid, red);
  float tau  = (s - 1.0f) * (1.0f / NEL);
  float prev = (float)NEL;
  for (int it = 0; it < 64; ++it) {
    float ss = 0.f, cc = 0.f;
    #pragma unroll
    for (int r = 0; r < 8; ++r) {
      int p = tid + (r << 8);
      if (p < NEL && vals[r] > tau) { ss += vals[r]; cc += 1.0f; }
    }
    bred2(ss, cc, tid, red);
    if (cc == prev || cc < 1.0f) break;
    float tn = (ss - 1.0f) / cc;
    prev = cc;
    if (tn <= tau) break;
    tau = tn;
  }
  float o = 0.f; d = 0.f;
  #pragma unroll
  for (int r = 0; r < 8; ++r) {
    float v = vals[r], a2 = v - tau;
    if (a2 > 0.f) o += v * a2;
  }
  bred2(o, d, tid, red);
  if (tid == 0) *outp = o;
}

// ---------------- fallback tier 2: fused dots from normalized bf16 ----------------
__global__ __launch_bounds__(256) void hcam_fused_bf(
    const u16* __restrict__ A, const u16* __restrict__ B,
    const int* __restrict__ ilen, const int* __restrict__ clen, float* __restrict__ out) {
  const int b = blockIdx.x;
  const int i = b >> 7, t = b & 127;
  const int tid = threadIdx.x;
  const int il = ilen[i], cl = clen[t];
  float vals[8];
  #pragma unroll
  for (int r = 0; r < 8; ++r) {
    int p = tid + (r << 8);
    float v = 0.f;
    if (p < NEL) {
      int k = p / LC, l = p - k * LC;
      if (k < il && l < cl) {
        const u16* ar = A + (size_t)(i * KI + k) * DD;
        const u16* br = B + (size_t)(t * LC + l) * DD;
        float s = 0.f;
        for (int dd = 0; dd < DD; dd += 8) {
          u16x8 av = *(const u16x8*)(ar + dd);
          u16x8 bv = *(const u16x8*)(br + dd);
          #pragma unroll
          for (int q = 0; q < 8; ++q) s += bf2f(av[q]) * bf2f(bv[q]);
        }
        v = s;
      }
    }
    vals[r] = v;
  }
  __shared__ float red[8];
  sparsemax_out(vals, tid, red, &out[b]);
}

// ---------------- fallback tier 3: fully fused, norms recomputed ----------------
__global__ __launch_bounds__(256) void hcam_fused_raw(
    const float* __restrict__ imgs, const float* __restrict__ caps,
    const int* __restrict__ ilen, const int* __restrict__ clen, float* __restrict__ out) {
  const int b = blockIdx.x;
  const int i = b >> 7, t = b & 127;
  const int tid = threadIdx.x;
  const int w = tid >> 6, lane = tid & 63;
  __shared__ float inv[KI + LC];
  for (int row = w; row < KI + LC; row += 4) {
    const float* src = (row < KI) ? imgs + (size_t)(i * KI + row) * DD
                                  : caps + (size_t)(t * LC + (row - KI)) * DD;
    float ss = 0.f;
    for (int e = lane; e < DD; e += 64) { float x = src[e] + EPSF; ss += x * x; }
    #pragma unroll
    for (int m = 32; m; m >>= 1) ss += __shfl_xor(ss, m);
    if (lane == 0) inv[row] = 1.0f / sqrtf(ss);
  }
  __syncthreads();
  const int il = ilen[i], cl = clen[t];
  float vals[8];
  #pragma unroll
  for (int r = 0; r < 8; ++r) {
    int p = tid + (r << 8);
    float v = 0.f;
    if (p < NEL) {
      int k = p / LC, l = p - k * LC;
      if (k < il && l < cl) {
        const float* ar = imgs + (size_t)(i * KI + k) * DD;
        const float* br = caps + (size_t)(t * LC + l) * DD;
        float s = 0.f;
        for (int dd = 0; dd < DD; dd += 4) {
          float4 a4 = *(const float4*)(ar + dd);
          float4 b4 = *(const float4*)(br + dd);
          s += (a4.x + EPSF) * (b4.x + EPSF) + (a4.y + EPSF) * (b4.y + EPSF)
             + (a4.z + EPSF) * (b4.z + EPSF) + (a4.w + EPSF) * (b4.w + EPSF);
        }
        v = s * inv[k] * inv[KI + l];
      }
    }
    vals[r] = v;
  }
  __shared__ float red[8];
  sparsemax_out(vals, tid, red, &out[b]);
}

extern "C" void kernel_launch(void* const* d_in, const int* in_sizes, int n_in,
                              void* d_out, int out_size, void* d_ws, size_t ws_size,
                              hipStream_t stream) {
  (void)in_sizes; (void)n_in; (void)out_size;
  const float* imgs = (const float*)d_in[1];
  const float* caps = (const float*)d_in[3];
  const int*   ilen = (const int*)d_in[4];
  const int*   clen = (const int*)d_in[5];
  float* out = (float*)d_out;

  const size_t offB     = (size_t)GM * DD * sizeof(u16);
  const size_t offC     = offB + (size_t)GN * DD * sizeof(u16);
  const size_t needFull = offC + (size_t)GM * GN * sizeof(_Float16);
  u16*      A = (u16*)d_ws;
  u16*      B = (u16*)((char*)d_ws + offB);
  _Float16* C = (_Float16*)((char*)d_ws + offC);

  if (ws_size >= needFull) {
    hcam_normcast<<<dim3(GM + GN), dim3(256), 0, stream>>>(imgs, caps, A, B);
    hcam_gemm16<<<dim3(MT * NTT), dim3(1024), 0, stream>>>(A, B, C);
    hcam_spmax_w<<<dim3(NBI * NBT / 4), dim3(256), 0, stream>>>(C, ilen, clen, out);
  } else if (ws_size >= offC) {
    hcam_normcast<<<dim3(GM + GN), dim3(256), 0, stream>>>(imgs, caps, A, B);
    hcam_fused_bf<<<dim3(NBI * NBT), dim3(256), 0, stream>>>(A, B, ilen, clen, out);
  } else {
    hcam_fused_raw<<<dim3(NBI * NBT), dim3(256), 0, stream>>>(imgs, caps, ilen, clen, out);
  }
}

// Round 7
// 124.434 us; speedup vs baseline: 1.1790x; 1.0189x over previous
//
#include <hip/hip_runtime.h>
#include <stdint.h>

#define EPSF 1e-6f

typedef unsigned short u16;
typedef __attribute__((ext_vector_type(8))) u16 u16x8;
typedef __attribute__((ext_vector_type(8))) __bf16 bf16x8;
typedef __attribute__((ext_vector_type(4))) float f32x4;

static constexpr int NBI = 128, NBT = 128, KI = 36, LC = 50, DD = 1024;
static constexpr int NEL = KI * LC;   // 1800
static constexpr int GM  = NBI * KI;  // 4608
static constexpr int GN  = NBT * LC;  // 6400
static constexpr int BM = 256, BN = 256, BK = 64;
static constexpr int KT  = DD / BK;   // 16
static constexpr int MT  = GM / BM;   // 18
static constexpr int NTT = GN / BN;   // 25
static constexpr int TB  = BM * BK;   // 16384 elems

static __device__ __forceinline__ u16 f2bf(float f) {  // RNE
  uint32_t u = __float_as_uint(f);
  u += 0x7fffu + ((u >> 16) & 1u);
  return (u16)(u >> 16);
}
static __device__ __forceinline__ float bf2f(u16 h) {
  return __uint_as_float((uint32_t)h << 16);
}

typedef __attribute__((address_space(1))) void gv_t;
typedef __attribute__((address_space(3))) void lv_t;
static __device__ __forceinline__ void gload16(const void* g, void* l) {
  __builtin_amdgcn_global_load_lds((const gv_t*)g, (lv_t*)l, 16, 0, 0);
}

// ---------------- kernel 0: add EPS, L2-normalize rows, cast to bf16 ----------------
__global__ __launch_bounds__(256) void hcam_normcast(
    const float* __restrict__ imgs, const float* __restrict__ caps,
    u16* __restrict__ A, u16* __restrict__ B) {
  int r = blockIdx.x;
  const float* src; u16* dst;
  if (r < GM) { src = imgs + (size_t)r * DD;        dst = A + (size_t)r * DD; }
  else        { src = caps + (size_t)(r - GM) * DD; dst = B + (size_t)(r - GM) * DD; }
  int tid = threadIdx.x;
  float4 v = *(const float4*)(src + tid * 4);
  v.x += EPSF; v.y += EPSF; v.z += EPSF; v.w += EPSF;
  float ss = v.x * v.x + v.y * v.y + v.z * v.z + v.w * v.w;
  #pragma unroll
  for (int m = 32; m; m >>= 1) ss += __shfl_xor(ss, m);
  __shared__ float wsum[4];
  if ((tid & 63) == 0) wsum[tid >> 6] = ss;
  __syncthreads();
  float inv = 1.0f / sqrtf(wsum[0] + wsum[1] + wsum[2] + wsum[3]);
  ushort4 o = make_ushort4(f2bf(v.x * inv), f2bf(v.y * inv), f2bf(v.z * inv), f2bf(v.w * inv));
  *(ushort4*)(dst + tid * 4) = o;
}

// ---------------- kernel 1: C = A * B^T, 256x256, BK=64, 8 waves, frag-reuse -------
// R5 post-mortem: 16-wave k2-outer SPILLED (WRITE_SIZE +21MB) under the 128-VGPR
// cap. This: 8 waves (512 thr, launch_bounds(512,2) -> 256 VGPR budget), wave out
// 128x64, frags read ONCE per K-tile with cross-quadrant reuse = 24 ds_read_b128
// per wave per tile = 0.375 KB/MFMA (m201's ratio). Live regs: A 8 + B 8 frags
// (64 VGPR) + acc 32 f32x4 (128) ~= 220 < 256, no spill. Schedule: R2's proven
// 2-barrier-per-tile + counted vmcnt(2); swizzle per rule #21; fp16 C.
__global__ __launch_bounds__(512, 2) void hcam_gemm8r(
    const u16* __restrict__ A, const u16* __restrict__ B, _Float16* __restrict__ C) {
  __shared__ u16 As[2 * TB];
  __shared__ u16 Bs[2 * TB];

  const int nwg = MT * NTT;
  int orig = blockIdx.x;
  int qq = nwg >> 3, rr = nwg & 7;
  int xcd = orig & 7, idx = orig >> 3;
  int wg = (xcd < rr ? xcd * (qq + 1) : rr * (qq + 1) + (xcd - rr) * qq) + idx;
  const int bm = wg % MT, bn = wg / MT;

  const int tid = threadIdx.x, lane = tid & 63, w = tid >> 6;
  const int wm = w >> 2, wn = w & 3;          // 2(M) x 4(N) waves, 128x64 out each
  const u16* Ag = A + (size_t)(bm * BM) * DD;
  const u16* Bg = B + (size_t)(bn * BN) * DD;

  const int srow = tid >> 3;                  // 0..63
  const int sc16 = (tid & 7) ^ (srow & 7);    // inverse-swizzled col16 (rule #21)
  const int wbase = w * 8;                    // wave-uniform LDS row base

  // stage one half-tile (128 rows x BK) = 2 gload16/thread
  auto stage = [&](const u16* g, u16* lds, int kt, int h) {
    #pragma unroll
    for (int j = 0; j < 2; ++j) {
      int row = h * 128 + j * 64 + srow;
      gload16(g + (size_t)row * DD + kt * BK + sc16 * 8,
              lds + (h * 128 + j * 64 + wbase) * BK);
    }
  };

  f32x4 acc[8][4];
  #pragma unroll
  for (int i = 0; i < 8; ++i)
    #pragma unroll
    for (int j = 0; j < 4; ++j) acc[i][j] = (f32x4){0.f, 0.f, 0.f, 0.f};

  const int fr = lane & 15, g4 = lane >> 4;

  // swizzled read offset for column-group c16 at this lane's frag-row
  auto rdoff = [&](int rowl, int k2) {
    const int c16 = k2 * 4 + g4;
    return rowl * BK + ((c16 ^ (fr & 7)) << 3);
  };

  // one K-tile of compute; frag-reuse phase order, 24 reads + 64 MFMA per wave
  auto ktile_compute = [&](const u16* as_c, const u16* bs_c, bool st,
                           u16* as_n, u16* bs_n, int tn) {
    bf16x8 af[4][2], blo[2][2], bhi[2][2];
    // ph0: A-lo + B-lo
    #pragma unroll
    for (int mi = 0; mi < 4; ++mi)
      #pragma unroll
      for (int k2 = 0; k2 < 2; ++k2)
        af[mi][k2] = __builtin_bit_cast(bf16x8,
            *(const u16x8*)(as_c + rdoff(wm * 128 + mi * 16 + fr, k2)));
    #pragma unroll
    for (int ni = 0; ni < 2; ++ni)
      #pragma unroll
      for (int k2 = 0; k2 < 2; ++k2)
        blo[ni][k2] = __builtin_bit_cast(bf16x8,
            *(const u16x8*)(bs_c + rdoff(wn * 64 + ni * 16 + fr, k2)));
    if (st) stage(Bg, bs_n, tn, 0);
    __builtin_amdgcn_s_setprio(1);
    #pragma unroll
    for (int k2 = 0; k2 < 2; ++k2)
      #pragma unroll
      for (int mi = 0; mi < 4; ++mi)
        #pragma unroll
        for (int ni = 0; ni < 2; ++ni)
          acc[mi][ni] = __builtin_amdgcn_mfma_f32_16x16x32_bf16(
              af[mi][k2], blo[ni][k2], acc[mi][ni], 0, 0, 0);
    __builtin_amdgcn_s_setprio(0);
    // ph1: B-hi
    #pragma unroll
    for (int ni = 0; ni < 2; ++ni)
      #pragma unroll
      for (int k2 = 0; k2 < 2; ++k2)
        bhi[ni][k2] = __builtin_bit_cast(bf16x8,
            *(const u16x8*)(bs_c + rdoff(wn * 64 + 32 + ni * 16 + fr, k2)));
    if (st) stage(Ag, as_n, tn, 1);
    __builtin_amdgcn_s_setprio(1);
    #pragma unroll
    for (int k2 = 0; k2 < 2; ++k2)
      #pragma unroll
      for (int mi = 0; mi < 4; ++mi)
        #pragma unroll
        for (int ni = 0; ni < 2; ++ni)
          acc[mi][2 + ni] = __builtin_amdgcn_mfma_f32_16x16x32_bf16(
              af[mi][k2], bhi[ni][k2], acc[mi][2 + ni], 0, 0, 0);
    __builtin_amdgcn_s_setprio(0);
    // ph2: A-hi (overwrite af)
    #pragma unroll
    for (int mi = 0; mi < 4; ++mi)
      #pragma unroll
      for (int k2 = 0; k2 < 2; ++k2)
        af[mi][k2] = __builtin_bit_cast(bf16x8,
            *(const u16x8*)(as_c + rdoff(wm * 128 + 64 + mi * 16 + fr, k2)));
    if (st) stage(Bg, bs_n, tn, 1);
    __builtin_amdgcn_s_setprio(1);
    #pragma unroll
    for (int k2 = 0; k2 < 2; ++k2)
      #pragma unroll
      for (int mi = 0; mi < 4; ++mi)
        #pragma unroll
        for (int ni = 0; ni < 2; ++ni)
          acc[4 + mi][ni] = __builtin_amdgcn_mfma_f32_16x16x32_bf16(
              af[mi][k2], blo[ni][k2], acc[4 + mi][ni], 0, 0, 0);
    __builtin_amdgcn_s_setprio(0);
    // ph3: no reads
    __builtin_amdgcn_s_setprio(1);
    #pragma unroll
    for (int k2 = 0; k2 < 2; ++k2)
      #pragma unroll
      for (int mi = 0; mi < 4; ++mi)
        #pragma unroll
        for (int ni = 0; ni < 2; ++ni)
          acc[4 + mi][2 + ni] = __builtin_amdgcn_mfma_f32_16x16x32_bf16(
              af[mi][k2], bhi[ni][k2], acc[4 + mi][2 + ni], 0, 0, 0);
    __builtin_amdgcn_s_setprio(0);
  };

  auto tile = [&](int t, const u16* as_c, const u16* bs_c, u16* as_n, u16* bs_n) {
    const int tn = t + 1;
    if (tn < KT) {
      stage(Ag, as_n, tn, 0);                            // A-h0(t+1)
      asm volatile("s_waitcnt vmcnt(2)" ::: "memory");   // tile t fully landed
    } else {
      asm volatile("s_waitcnt vmcnt(0)" ::: "memory");
    }
    __builtin_amdgcn_s_barrier();                        // tile-ready
    __builtin_amdgcn_sched_barrier(0);
    ktile_compute(as_c, bs_c, tn < KT, as_n, bs_n, tn);
    __builtin_amdgcn_s_barrier();                        // reads of cur done
    __builtin_amdgcn_sched_barrier(0);
  };

  // prologue: tile 0 (4 halves) + A-h0(1) -> 10 loads/thread in flight
  stage(Ag, As, 0, 0); stage(Bg, Bs, 0, 0);
  stage(Ag, As, 0, 1); stage(Bg, Bs, 0, 1);
  stage(Ag, As + TB, 1, 0);
  asm volatile("s_waitcnt vmcnt(2)" ::: "memory");
  __builtin_amdgcn_s_barrier();
  __builtin_amdgcn_sched_barrier(0);
  ktile_compute(As, Bs, true, As + TB, Bs + TB, 1);      // tile 0
  __builtin_amdgcn_s_barrier();
  __builtin_amdgcn_sched_barrier(0);

  #pragma unroll 1
  for (int tp = 1; tp + 1 < KT; tp += 2) {
    tile(tp,     As + TB, Bs + TB, As,      Bs);
    tile(tp + 1, As,      Bs,      As + TB, Bs + TB);
  }
  tile(KT - 1, As + TB, Bs + TB, As, Bs);   // tile 15

  // C/D layout: col = lane&15, row = (lane>>4)*4 + j (m89-verified)
  const int fc = lane & 15, fq = (lane >> 4) * 4;
  #pragma unroll
  for (int mh = 0; mh < 2; ++mh)
    #pragma unroll
    for (int mi = 0; mi < 4; ++mi)
      #pragma unroll
      for (int an = 0; an < 4; ++an) {
        const int row0 = bm * BM + wm * 128 + mh * 64 + mi * 16 + fq;
        const int col  = bn * BN + wn * 64 + an * 16 + fc;
        #pragma unroll
        for (int j = 0; j < 4; ++j)
          C[(size_t)(row0 + j) * GN + col] = (_Float16)acc[mh * 4 + mi][an][j];
      }
}

// ---------------- kernel 2: wave-per-row sparsemax + weighted sum (fp16 C) ---------
static constexpr int RPT = (NEL + 63) / 64;   // 29

__global__ __launch_bounds__(256) void hcam_spmax_w(
    const _Float16* __restrict__ C, const int* __restrict__ ilen, const int* __restrict__ clen,
    float* __restrict__ out) {
  const int wid  = blockIdx.x * 4 + (threadIdx.x >> 6);
  const int lane = threadIdx.x & 63;
  const int i = wid >> 7, t = wid & 127;
  const int il = ilen[i], cl = clen[t];
  const _Float16* base = C + (size_t)i * KI * GN + t * LC;

  float v[RPT];
  float sum = 0.f;
  #pragma unroll
  for (int r = 0; r < RPT; ++r) {
    int p = lane + (r << 6);
    float x = -1e30f;
    if (p < NEL) {
      int k = p / LC, l = p - k * LC;
      if (k < il && l < cl) { x = (float)base[(size_t)k * GN + l]; sum += x; }
    }
    v[r] = x;
  }
  #pragma unroll
  for (int m = 32; m; m >>= 1) sum += __shfl_xor(sum, m);

  const float mzero = (float)(NEL - il * cl);
  float tau  = (sum - 1.0f) * (1.0f / NEL);
  float prev = (float)NEL;
  for (int it = 0; it < 32; ++it) {
    float ss = 0.f, cc = 0.f;
    #pragma unroll
    for (int r = 0; r < RPT; ++r) {
      if (v[r] > tau) { ss += v[r]; cc += 1.0f; }
    }
    #pragma unroll
    for (int m = 32; m; m >>= 1) { ss += __shfl_xor(ss, m); cc += __shfl_xor(cc, m); }
    if (tau < 0.f) cc += mzero;
    if (cc == prev || cc < 1.0f) break;
    float tn = (ss - 1.0f) / cc;
    prev = cc;
    if (tn <= tau) break;
    tau = tn;
  }

  float o = 0.f;
  #pragma unroll
  for (int r = 0; r < RPT; ++r) {
    float d = v[r] - tau;
    if (d > 0.f) o += v[r] * d;
  }
  #pragma unroll
  for (int m = 32; m; m >>= 1) o += __shfl_xor(o, m);
  if (lane == 0) out[wid] = o;
}

// ---------------- block reduction of two floats (fallback path) ----------------
static __device__ __forceinline__ void bred2(float& a, float& b2, int tid, float* red) {
  #pragma unroll
  for (int m = 32; m; m >>= 1) { a += __shfl_xor(a, m); b2 += __shfl_xor(b2, m); }
  __syncthreads();
  if ((tid & 63) == 0) { red[(tid >> 6) * 2] = a; red[(tid >> 6) * 2 + 1] = b2; }
  __syncthreads();
  a  = red[0] + red[2] + red[4] + red[6];
  b2 = red[1] + red[3] + red[5] + red[7];
}

static __device__ __forceinline__ void sparsemax_out(float vals[8], int tid, float* red, float* outp) {
  float s = 0.f, d = 0.f;
  #pragma unroll
  for (int r = 0; r < 8; ++r) { int p = tid + (r << 8); if (p < NEL) s += vals[r]; }
  bred2(s, d, tid, red);
  float tau  = (s - 1.0f) * (1.0f / NEL);
  float prev = (float)NEL;
  for (int it = 0; it < 64; ++it) {
    float ss = 0.f, cc = 0.f;
    #pragma unroll
    for (int r = 0; r < 8; ++r) {
      int p = tid + (r << 8);
      if (p < NEL && vals[r] > tau) { ss += vals[r]; cc += 1.0f; }
    }
    bred2(ss, cc, tid, red);
    if (cc == prev || cc < 1.0f) break;
    float tn = (ss - 1.0f) / cc;
    prev = cc;
    if (tn <= tau) break;
    tau = tn;
  }
  float o = 0.f; d = 0.f;
  #pragma unroll
  for (int r = 0; r < 8; ++r) {
    float v = vals[r], a2 = v - tau;
    if (a2 > 0.f) o += v * a2;
  }
  bred2(o, d, tid, red);
  if (tid == 0) *outp = o;
}

// ---------------- fallback tier 2: fused dots from normalized bf16 ----------------
__global__ __launch_bounds__(256) void hcam_fused_bf(
    const u16* __restrict__ A, const u16* __restrict__ B,
    const int* __restrict__ ilen, const int* __restrict__ clen, float* __restrict__ out) {
  const int b = blockIdx.x;
  const int i = b >> 7, t = b & 127;
  const int tid = threadIdx.x;
  const int il = ilen[i], cl = clen[t];
  float vals[8];
  #pragma unroll
  for (int r = 0; r < 8; ++r) {
    int p = tid + (r << 8);
    float v = 0.f;
    if (p < NEL) {
      int k = p / LC, l = p - k * LC;
      if (k < il && l < cl) {
        const u16* ar = A + (size_t)(i * KI + k) * DD;
        const u16* br = B + (size_t)(t * LC + l) * DD;
        float s = 0.f;
        for (int dd = 0; dd < DD; dd += 8) {
          u16x8 av = *(const u16x8*)(ar + dd);
          u16x8 bv = *(const u16x8*)(br + dd);
          #pragma unroll
          for (int q = 0; q < 8; ++q) s += bf2f(av[q]) * bf2f(bv[q]);
        }
        v = s;
      }
    }
    vals[r] = v;
  }
  __shared__ float red[8];
  sparsemax_out(vals, tid, red, &out[b]);
}

// ---------------- fallback tier 3: fully fused, norms recomputed ----------------
__global__ __launch_bounds__(256) void hcam_fused_raw(
    const float* __restrict__ imgs, const float* __restrict__ caps,
    const int* __restrict__ ilen, const int* __restrict__ clen, float* __restrict__ out) {
  const int b = blockIdx.x;
  const int i = b >> 7, t = b & 127;
  const int tid = threadIdx.x;
  const int w = tid >> 6, lane = tid & 63;
  __shared__ float inv[KI + LC];
  for (int row = w; row < KI + LC; row += 4) {
    const float* src = (row < KI) ? imgs + (size_t)(i * KI + row) * DD
                                  : caps + (size_t)(t * LC + (row - KI)) * DD;
    float ss = 0.f;
    for (int e = lane; e < DD; e += 64) { float x = src[e] + EPSF; ss += x * x; }
    #pragma unroll
    for (int m = 32; m; m >>= 1) ss += __shfl_xor(ss, m);
    if (lane == 0) inv[row] = 1.0f / sqrtf(ss);
  }
  __syncthreads();
  const int il = ilen[i], cl = clen[t];
  float vals[8];
  #pragma unroll
  for (int r = 0; r < 8; ++r) {
    int p = tid + (r << 8);
    float v = 0.f;
    if (p < NEL) {
      int k = p / LC, l = p - k * LC;
      if (k < il && l < cl) {
        const float* ar = imgs + (size_t)(i * KI + k) * DD;
        const float* br = caps + (size_t)(t * LC + l) * DD;
        float s = 0.f;
        for (int dd = 0; dd < DD; dd += 4) {
          float4 a4 = *(const float4*)(ar + dd);
          float4 b4 = *(const float4*)(br + dd);
          s += (a4.x + EPSF) * (b4.x + EPSF) + (a4.y + EPSF) * (b4.y + EPSF)
             + (a4.z + EPSF) * (b4.z + EPSF) + (a4.w + EPSF) * (b4.w + EPSF);
        }
        v = s * inv[k] * inv[KI + l];
      }
    }
    vals[r] = v;
  }
  __shared__ float red[8];
  sparsemax_out(vals, tid, red, &out[b]);
}

extern "C" void kernel_launch(void* const* d_in, const int* in_sizes, int n_in,
                              void* d_out, int out_size, void* d_ws, size_t ws_size,
                              hipStream_t stream) {
  (void)in_sizes; (void)n_in; (void)out_size;
  const float* imgs = (const float*)d_in[1];
  const float* caps = (const float*)d_in[3];
  const int*   ilen = (const int*)d_in[4];
  const int*   clen = (const int*)d_in[5];
  float* out = (float*)d_out;

  const size_t offB     = (size_t)GM * DD * sizeof(u16);
  const size_t offC     = offB + (size_t)GN * DD * sizeof(u16);
  const size_t needFull = offC + (size_t)GM * GN * sizeof(_Float16);
  u16*      A = (u16*)d_ws;
  u16*      B = (u16*)((char*)d_ws + offB);
  _Float16* C = (_Float16*)((char*)d_ws + offC);

  if (ws_size >= needFull) {
    hcam_normcast<<<dim3(GM + GN), dim3(256), 0, stream>>>(imgs, caps, A, B);
    hcam_gemm8r<<<dim3(MT * NTT), dim3(512), 0, stream>>>(A, B, C);
    hcam_spmax_w<<<dim3(NBI * NBT / 4), dim3(256), 0, stream>>>(C, ilen, clen, out);
  } else if (ws_size >= offC) {
    hcam_normcast<<<dim3(GM + GN), dim3(256), 0, stream>>>(imgs, caps, A, B);
    hcam_fused_bf<<<dim3(NBI * NBT), dim3(256), 0, stream>>>(A, B, ilen, clen, out);
  } else {
    hcam_fused_raw<<<dim3(NBI * NBT), dim3(256), 0, stream>>>(imgs, caps, ilen, clen, out);
  }
}